// Round 4
// baseline (35.371 us; speedup 1.0000x reference)
//
#include <hip/hip_runtime.h>
#include <hip/hip_bf16.h>

#define K_DIM 4096
#define N_DIM 11008

typedef __attribute__((ext_vector_type(4))) float f32x4;
typedef _Float16 half8 __attribute__((ext_vector_type(8)));
typedef _Float16 half2v __attribute__((ext_vector_type(2)));
typedef unsigned int uint32;

// ---------------- prep: x[64,4096] f32 -> xp f16, fragment-major, AWQ-permuted
// xp slot (kg, h, mt): halfword offset (kg*8 + h*4 + mt)*512 + lane*8.
// Lane element e: m = mt*16+(lane&15); k' = h*32+(lane>>4)*8+e;
//   t = k'>>2, i' = k'&3, i = ((i'&1)<<1)|(i'>>1); col = (t>=8?32:0)+(t&7)+8i
// (mapping validated: rounds 1-3 pass correctness)
__global__ __launch_bounds__(256) void prep_x(const float* __restrict__ x,
                                              unsigned short* __restrict__ xp) {
    const int g = blockIdx.x * 256 + threadIdx.x;      // 0..32767
    const int lane = g & 63, mt = (g >> 6) & 3, h = (g >> 8) & 1, kg = g >> 9;
    const int m = mt * 16 + (lane & 15), qq = lane >> 4;
    union { unsigned short v[8]; uint4 u4; } r;
#pragma unroll
    for (int e = 0; e < 8; ++e) {
        const int kp = h * 32 + qq * 8 + e;
        const int t = kp >> 2, ip = kp & 3;
        const int i = ((ip & 1) << 1) | (ip >> 1);
        const int col = ((t >> 3) << 5) + (t & 7) + (i << 3);
        const _Float16 hf = (_Float16)x[m * K_DIM + kg * 64 + col];
        r.v[e] = __builtin_bit_cast(unsigned short, hf);
    }
    *(uint4*)(xp + (size_t)g * 8) = r.u4;
}

// ---------------- dequant 2 packed words -> one B-fragment (8 f16, k'-ordered)
__device__ __forceinline__ half8 build_bfrag(int w0, int w1, half2v s2, half2v c2) {
    union { half8 h; half2v p[4]; } r;
    const half2v k1024 = {(_Float16)1024.0f, (_Float16)1024.0f};
    const uint32 u0 = (uint32)(w0 & 0xF)        | (((uint32)w0 & 0xF00u) << 8) | 0x64006400u;
    const uint32 u1 = (uint32)((w0 >> 4) & 0xF) | (((uint32)w0 & 0xF000u) << 4) | 0x64006400u;
    const uint32 u2 = (uint32)(w1 & 0xF)        | (((uint32)w1 & 0xF00u) << 8) | 0x64006400u;
    const uint32 u3 = (uint32)((w1 >> 4) & 0xF) | (((uint32)w1 & 0xF000u) << 4) | 0x64006400u;
    half2v q;
    q = __builtin_bit_cast(half2v, u0) - k1024; r.p[0] = q * s2 + c2;
    q = __builtin_bit_cast(half2v, u1) - k1024; r.p[1] = q * s2 + c2;
    q = __builtin_bit_cast(half2v, u2) - k1024; r.p[2] = q * s2 + c2;
    q = __builtin_bit_cast(half2v, u3) - k1024; r.p[3] = q * s2 + c2;
    return r.h;
}

// ---------------- main GEMM: grid (172, 4), 256 thr (4 waves).
// Wave (nx, ky, j): output tile 64m x 64n (n0 = nx*64, 4 subtiles of 16n),
// K-slice kg in [ky*16 + j*4, +4). 2-deep register prefetch of the qw stream.
// Two-phase 32 KB LDS reduce over j -> 16 KB partial per WG into ws.
__global__ __launch_bounds__(256) void w4_gemm(
    const unsigned short* __restrict__ xp,   // f16, fragment-major, 512 KB
    const int*   __restrict__ qw,            // [2752, 4096] packed
    const float* __restrict__ scale,
    const float* __restrict__ zp,
    f32x4*       __restrict__ ws)            // [172*4][1024] f32x4 partials
{
    __shared__ f32x4 part[2048];             // 32 KB

    const int tid = threadIdx.x, lane = tid & 63, j = tid >> 6;
    const int nl = lane & 15, q = lane >> 4;
    const int nx = blockIdx.x, ky = blockIdx.y;
    const int n0 = nx * 64;

    // per-subtile dequant constants (static indices only)
    half2v s2[4], c2[4];
#pragma unroll
    for (int s = 0; s < 4; ++s) {
        const int nn = n0 + s * 16 + nl;
        const float sc = scale[nn], z = zp[nn];
        const _Float16 sh = (_Float16)sc, ch = (_Float16)(-z * sc);
        s2[s] = half2v{sh, sh};
        c2[s] = half2v{ch, ch};
    }

    // qw base for subtile s is qb + s*4*K_DIM (in ints)
    const int* qb = qw + ((size_t)((n0 >> 2) + (nl >> 2)) * K_DIM) + ((nl & 3) * 16) + 2 * q;

    f32x4 acc[4][4] = {};                    // [s][mt]
    const int kg0 = ky * 16 + j * 4;

    int2 qa[2][2][4];                        // [buf][h][s], static idx after unroll
    auto loadq = [&](int buf, int kg) {
#pragma unroll
        for (int s = 0; s < 4; ++s) {
            qa[buf][0][s] = *(const int2*)(qb + (size_t)s * 4 * K_DIM + kg * 64);
            qa[buf][1][s] = *(const int2*)(qb + (size_t)s * 4 * K_DIM + kg * 64 + 8);
        }
    };

    loadq(0, kg0);
#pragma unroll
    for (int it = 0; it < 4; ++it) {
        if (it < 3) loadq((it + 1) & 1, kg0 + it + 1);
        const int b = it & 1;
        const unsigned short* ab = xp + (size_t)(kg0 + it) * 4096;
#pragma unroll
        for (int h = 0; h < 2; ++h) {
            half8 bf[4];
#pragma unroll
            for (int s = 0; s < 4; ++s)
                bf[s] = build_bfrag(qa[b][h][s].x, qa[b][h][s].y, s2[s], c2[s]);
#pragma unroll
            for (int mt = 0; mt < 4; ++mt) {
                const half8 af = *(const half8*)(ab + (h * 4 + mt) * 512 + lane * 8);
#pragma unroll
                for (int s = 0; s < 4; ++s)
                    acc[s][mt] = __builtin_amdgcn_mfma_f32_16x16x32_f16(af, bf[s], acc[s][mt], 0, 0, 0);
            }
        }
    }

    // two-phase LDS reduce over j (phase p covers mt = 2p, 2p+1)
    f32x4* wsb = ws + ((size_t)nx * 4 + ky) * 1024;
#pragma unroll
    for (int p = 0; p < 2; ++p) {
#pragma unroll
        for (int mtl = 0; mtl < 2; ++mtl)
#pragma unroll
            for (int s = 0; s < 4; ++s)
                part[j * 512 + (mtl * 4 + s) * 64 + lane] = acc[s][p * 2 + mtl];
        __syncthreads();
#pragma unroll
        for (int ss = 0; ss < 2; ++ss) {
            const int slot = tid + ss * 256;
            f32x4 v = part[slot];
            v += part[512 + slot];
            v += part[1024 + slot];
            v += part[1536 + slot];
            wsb[p * 512 + slot] = v;
        }
        if (p == 0) __syncthreads();         // phase-0 reads done before phase-1 writes
    }
}

// ---------------- final reduce: sum 4 ky partials + bias -> out
__global__ __launch_bounds__(256) void reduce_k(
    const f32x4* __restrict__ ws,
    const float* __restrict__ bias,
    float*       __restrict__ out)
{
    const int nx = blockIdx.x, tid = threadIdx.x;
    const f32x4* wsb = ws + (size_t)nx * 4096;
#pragma unroll
    for (int uu = 0; uu < 4; ++uu) {
        const int u = tid + uu * 256;
        f32x4 v = wsb[u];
        v += wsb[1024 + u];
        v += wsb[2048 + u];
        v += wsb[3072 + u];
        const int p = u >> 9, slot = u & 511;
        const int mtl = slot >> 8, s = (slot >> 6) & 3, lane = slot & 63;
        const int qq = lane >> 4, nnl = lane & 15;
        const int mt = p * 2 + mtl;
        const int n = nx * 64 + s * 16 + nnl;
        const float bv = bias[n];
        const int m0 = mt * 16 + qq * 4;
#pragma unroll
        for (int r = 0; r < 4; ++r)
            out[(size_t)(m0 + r) * N_DIM + n] = v[r] + bv;
    }
}

extern "C" void kernel_launch(void* const* d_in, const int* in_sizes, int n_in,
                              void* d_out, int out_size, void* d_ws, size_t ws_size,
                              hipStream_t stream) {
    const float* x     = (const float*)d_in[0];
    const int*   qw    = (const int*)d_in[1];
    const float* scale = (const float*)d_in[2];
    const float* zp    = (const float*)d_in[3];
    const float* bias  = (const float*)d_in[4];
    float* out = (float*)d_out;

    unsigned short* xp = (unsigned short*)d_ws;                  // 512 KB
    f32x4* part_ws = (f32x4*)((char*)d_ws + (1 << 20));          // 11.3 MB partials

    prep_x<<<128, 256, 0, stream>>>(x, xp);
    dim3 grid(172, 4);
    w4_gemm<<<grid, 256, 0, stream>>>(xp, qw, scale, zp, part_ws);
    reduce_k<<<172, 256, 0, stream>>>(part_ws, bias, out);
}

// Round 5
// 29.587 us; speedup vs baseline: 1.1955x; 1.1955x over previous
//
#include <hip/hip_runtime.h>
#include <hip/hip_bf16.h>

#define K_DIM 4096
#define N_DIM 11008

typedef __attribute__((ext_vector_type(4))) float f32x4;
typedef _Float16 half8 __attribute__((ext_vector_type(8)));
typedef _Float16 half2v __attribute__((ext_vector_type(2)));
typedef unsigned int uint32;

// ---------------- prep: x[64,4096] f32 -> xp f16, fragment-major, AWQ-permuted
// xp slot (kg, h, mt): halfword offset (kg*8 + h*4 + mt)*512 + lane*8.
// Lane element e: m = mt*16+(lane&15); k' = h*32+(lane>>4)*8+e;
//   t = k'>>2, i' = k'&3, i = ((i'&1)<<1)|(i'>>1); col = (t>=8?32:0)+(t&7)+8i
// (mapping validated: rounds 1-4 pass correctness)
__global__ __launch_bounds__(256) void prep_x(const float* __restrict__ x,
                                              unsigned short* __restrict__ xp) {
    const int g = blockIdx.x * 256 + threadIdx.x;      // 0..32767
    const int lane = g & 63, mt = (g >> 6) & 3, h = (g >> 8) & 1, kg = g >> 9;
    const int m = mt * 16 + (lane & 15), qq = lane >> 4;
    union { unsigned short v[8]; uint4 u4; } r;
#pragma unroll
    for (int e = 0; e < 8; ++e) {
        const int kp = h * 32 + qq * 8 + e;
        const int t = kp >> 2, ip = kp & 3;
        const int i = ((ip & 1) << 1) | (ip >> 1);
        const int col = ((t >> 3) << 5) + (t & 7) + (i << 3);
        const _Float16 hf = (_Float16)x[m * K_DIM + kg * 64 + col];
        r.v[e] = __builtin_bit_cast(unsigned short, hf);
    }
    *(uint4*)(xp + (size_t)g * 8) = r.u4;
}

// ---------------- dequant 2 packed words -> one B-fragment (8 f16, k'-ordered)
__device__ __forceinline__ half8 build_bfrag(int w0, int w1, half2v s2, half2v c2) {
    union { half8 h; half2v p[4]; } r;
    const half2v k1024 = {(_Float16)1024.0f, (_Float16)1024.0f};
    const uint32 u0 = (uint32)(w0 & 0xF)        | (((uint32)w0 & 0xF00u) << 8) | 0x64006400u;
    const uint32 u1 = (uint32)((w0 >> 4) & 0xF) | (((uint32)w0 & 0xF000u) << 4) | 0x64006400u;
    const uint32 u2 = (uint32)(w1 & 0xF)        | (((uint32)w1 & 0xF00u) << 8) | 0x64006400u;
    const uint32 u3 = (uint32)((w1 >> 4) & 0xF) | (((uint32)w1 & 0xF000u) << 4) | 0x64006400u;
    half2v q;
    q = __builtin_bit_cast(half2v, u0) - k1024; r.p[0] = q * s2 + c2;
    q = __builtin_bit_cast(half2v, u1) - k1024; r.p[1] = q * s2 + c2;
    q = __builtin_bit_cast(half2v, u2) - k1024; r.p[2] = q * s2 + c2;
    q = __builtin_bit_cast(half2v, u3) - k1024; r.p[3] = q * s2 + c2;
    return r.h;
}

// ---------------- main GEMM: grid (344, 4), 256 thr (4 waves) — r3 geometry.
// Wave (nx, ky, j): 64m x 32n tile, kg in [ky*16 + j*4, +4).
// NEW vs r3: all 16 qw int2 loads issued upfront (independent), compute fully
// unrolled so A-frag loads pipeline under MFMAs. One HBM-latency exposure/wave.
__global__ __launch_bounds__(256) void w4_gemm(
    const unsigned short* __restrict__ xp,   // f16, fragment-major
    const int*   __restrict__ qw,            // [2752, 4096] packed
    const float* __restrict__ scale,
    const float* __restrict__ zp,
    f32x4*       __restrict__ ws)            // partials [344*4][512] f32x4
{
    __shared__ f32x4 part[2048];             // 32 KB

    const int tid = threadIdx.x, lane = tid & 63, j = tid >> 6;
    const int nl = lane & 15, q = lane >> 4;
    const int nx = blockIdx.x, ky = blockIdx.y;
    const int n0 = nx * 32;
    const int nnA = n0 + nl, nnB = n0 + 16 + nl;

    const float sA = scale[nnA], zA = zp[nnA];
    const float sB = scale[nnB], zB = zp[nnB];
    const _Float16 shA = (_Float16)sA, chA = (_Float16)(-zA * sA);
    const _Float16 shB = (_Float16)sB, chB = (_Float16)(-zB * sB);
    const half2v s2A = {shA, shA}, c2A = {chA, chA};
    const half2v s2B = {shB, shB}, c2B = {chB, chB};

    const int* qbA = qw + ((size_t)(nnA >> 2) * K_DIM) + ((nnA & 3) * 16) + 2 * q;
    const int* qbB = qw + ((size_t)(nnB >> 2) * K_DIM) + ((nnB & 3) * 16) + 2 * q;

    const int kg0 = ky * 16 + j * 4;

    // ---- issue ALL qw loads for this wave's slice upfront (16 independent)
    int2 qa[4][2][2];                        // [it][tile][h] — static idx (unrolled)
#pragma unroll
    for (int it = 0; it < 4; ++it) {
        const int off = (kg0 + it) * 64;
        qa[it][0][0] = *(const int2*)(qbA + off);
        qa[it][0][1] = *(const int2*)(qbA + off + 8);
        qa[it][1][0] = *(const int2*)(qbB + off);
        qa[it][1][1] = *(const int2*)(qbB + off + 8);
    }

    f32x4 acc[2][4] = {};                    // [tile][mt]
#pragma unroll
    for (int it = 0; it < 4; ++it) {
        const unsigned short* ab = xp + (size_t)(kg0 + it) * 4096;
#pragma unroll
        for (int h = 0; h < 2; ++h) {
            const half8 bfA = build_bfrag(qa[it][0][h].x, qa[it][0][h].y, s2A, c2A);
            const half8 bfB = build_bfrag(qa[it][1][h].x, qa[it][1][h].y, s2B, c2B);
#pragma unroll
            for (int mt = 0; mt < 4; ++mt) {
                const half8 af = *(const half8*)(ab + (h * 4 + mt) * 512 + lane * 8);
                acc[0][mt] = __builtin_amdgcn_mfma_f32_16x16x32_f16(af, bfA, acc[0][mt], 0, 0, 0);
                acc[1][mt] = __builtin_amdgcn_mfma_f32_16x16x32_f16(af, bfB, acc[1][mt], 0, 0, 0);
            }
        }
    }

    // partials: part[((j*2+nt)*4+mt)*64 + q*16 + nl]  (identical to r3)
#pragma unroll
    for (int nt = 0; nt < 2; ++nt)
#pragma unroll
        for (int mt = 0; mt < 4; ++mt)
            part[((j * 2 + nt) * 4 + mt) * 64 + q * 16 + nl] = acc[nt][mt];
    __syncthreads();

    f32x4* wsb = ws + ((size_t)nx * 4 + ky) * 512;
#pragma unroll
    for (int ss = 0; ss < 2; ++ss) {
        const int s = tid + ss * 256;
        f32x4 v = part[s];
        v += part[512 + s];
        v += part[1024 + s];
        v += part[1536 + s];
        wsb[s] = v;
    }
}

// ---------------- final reduce: sum 4 ky partials + bias -> out (r3 verbatim)
__global__ __launch_bounds__(256) void reduce_k(
    const f32x4* __restrict__ ws,
    const float* __restrict__ bias,
    float*       __restrict__ out)
{
    const int nx = blockIdx.x, tid = threadIdx.x;
    const f32x4* wsb = ws + (size_t)nx * 4 * 512;
#pragma unroll
    for (int ss = 0; ss < 2; ++ss) {
        const int s = tid + ss * 256;
        f32x4 v = wsb[s];
        v += wsb[512 + s];
        v += wsb[1024 + s];
        v += wsb[1536 + s];
        const int nt = s >> 8, mt = (s >> 6) & 3, qq = (s >> 4) & 3, nl = s & 15;
        const int n = nx * 32 + nt * 16 + nl;
        const float bv = bias[n];
        const int m0 = mt * 16 + qq * 4;
#pragma unroll
        for (int r = 0; r < 4; ++r)
            out[(size_t)(m0 + r) * N_DIM + n] = v[r] + bv;
    }
}

extern "C" void kernel_launch(void* const* d_in, const int* in_sizes, int n_in,
                              void* d_out, int out_size, void* d_ws, size_t ws_size,
                              hipStream_t stream) {
    const float* x     = (const float*)d_in[0];
    const int*   qw    = (const int*)d_in[1];
    const float* scale = (const float*)d_in[2];
    const float* zp    = (const float*)d_in[3];
    const float* bias  = (const float*)d_in[4];
    float* out = (float*)d_out;

    unsigned short* xp = (unsigned short*)d_ws;                  // 512 KB
    f32x4* part_ws = (f32x4*)((char*)d_ws + (1 << 20));          // 5.6 MB partials

    prep_x<<<128, 256, 0, stream>>>(x, xp);
    dim3 grid(344, 4);
    w4_gemm<<<grid, 256, 0, stream>>>(xp, qw, scale, zp, part_ws);
    reduce_k<<<344, 256, 0, stream>>>(part_ws, bias, out);
}